// Round 3
// baseline (1378.511 us; speedup 1.0000x reference)
//
#include <hip/hip_runtime.h>
#include <cfloat>
#include <climits>

// Problem constants: x (16,2048,256) fp32 -> N=32768 rows; weight (4096,256) fp32.
constexpr int E  = 256;    // quantizing_dim
constexpr int Qn = 4096;   // num_quantizing
constexpr float WSCALE = 4096.0f;   // 2^12 exact pow2 (keeps f16 products well-scaled)

// Round 14: revert K-loop to round-12 (92.2 us validated; round-13's fine
// phases regressed: 64B rows -> only 2 swizzle bits -> +70% conflict cost, and
// counted-vmcnt needs >=3 prefetch slots which 128KB LDS can't hold at BK=64
// with 128B rows). New: finalize is FUSED into vq_mfma via last-block ticket
// (per row-band counter, device-scope fence + atomicAdd; winner block runs the
// verbatim finalize math for its 256 rows). Saves the third kernel dispatch
// and overlaps the merge/rescore with remaining GEMM blocks. Counters zeroed
// by prep block 0 (kernel-boundary ordering). GEMM numerics byte-identical.

typedef _Float16 half8  __attribute__((ext_vector_type(8)));
typedef _Float16 half4v __attribute__((ext_vector_type(4)));
typedef float    f32x16 __attribute__((ext_vector_type(16)));

#define GAS __attribute__((address_space(1)))
#define LAS __attribute__((address_space(3)))

#define NEG_INF __int_as_float(0xFF800000)

__device__ inline bool lexlt(float a, int ai, float b, int bi) {
    return a < b || (a == b && ai < bi);
}

// ---------------------------------------------------------------------------
// Prep: one 64-lane wave per row (x and w). Emits f16 operand; sumsq only for w.
// Also zeroes the 128 row-band tickets (block 0).
// ---------------------------------------------------------------------------
__global__ __launch_bounds__(256) void prep_kernel(
    const float* __restrict__ x, const float* __restrict__ w,
    _Float16* __restrict__ A16, _Float16* __restrict__ B16,
    float* __restrict__ w2, int* __restrict__ counters, int nxblocks)
{
    int blk  = blockIdx.x;
    int sub  = threadIdx.x >> 6;
    int lane = threadIdx.x & 63;
    bool isX = blk < nxblocks;
    int row  = (isX ? blk : blk - nxblocks) * 4 + sub;

    if (blk == 0 && threadIdx.x < 128) counters[threadIdx.x] = 0;

    const float* src = isX ? x : w;
    float4 v = *(const float4*)(src + (size_t)row * E + lane * 4);

    if (!isX) {
        float s = v.x * v.x + v.y * v.y + v.z * v.z + v.w * v.w;   // UNSCALED sumsq
        #pragma unroll
        for (int off = 32; off; off >>= 1) s += __shfl_xor(s, off);
        if (lane == 0) w2[row] = s;
    }

    float sc = isX ? 1.0f : WSCALE;                            // exact pow2
    half4v h = { (_Float16)(v.x * sc), (_Float16)(v.y * sc),
                 (_Float16)(v.z * sc), (_Float16)(v.w * sc) };
    _Float16* dst16 = (isX ? A16 : B16) + (size_t)row * 256;
    *(half4v*)(dst16 + lane * 4) = h;
}

// ---------------------------------------------------------------------------
// Finalize body (verbatim round-9-validated math), one 64-lane wave per row:
// 32 cg x top-4 packed candidates -> global top-4 by packed key -> exact fp32
// rescore (reference formula + first-index tie-break), write outputs.
// ---------------------------------------------------------------------------
__device__ __forceinline__ void finalize_row(
    int row, int lane,
    const float4* __restrict__ top4, const float* __restrict__ x,
    const float* __restrict__ w, const float* __restrict__ w2,
    float* __restrict__ qdata, float* __restrict__ qidx)
{
    float cand[4];
    if (lane < 32) {
        float4 c4 = top4[(size_t)row * 32 + lane];
        cand[0] = c4.x; cand[1] = c4.y; cand[2] = c4.z; cand[3] = c4.w;
    } else {
        cand[0] = cand[1] = cand[2] = cand[3] = NEG_INF;
    }

    int chosen[4];
    #pragma unroll
    for (int p = 0; p < 4; ++p) {
        float cur = fmaxf(fmaxf(cand[0], cand[1]), fmaxf(cand[2], cand[3]));
        #pragma unroll
        for (int off = 32; off; off >>= 1)
            cur = fmaxf(cur, __shfl_xor(cur, off));
        int curb = __float_as_int(cur);
        chosen[p] = curb & 0xFFF;
        #pragma unroll
        for (int j = 0; j < 4; ++j)
            if (__float_as_int(cand[j]) == curb) cand[j] = NEG_INF;
    }

    // exact fp32 rescore of the 4 survivors; X2 via the same data layout +
    // butterfly order as the validated prep reduction.
    float4 xv = *(const float4*)(x + (size_t)row * E + lane * 4);
    float s2 = xv.x * xv.x + xv.y * xv.y + xv.z * xv.z + xv.w * xv.w;
    float d[4];
    #pragma unroll
    for (int j = 0; j < 4; ++j) {
        float4 wv = *(const float4*)(w + (size_t)chosen[j] * E + lane * 4);
        d[j] = xv.x * wv.x + xv.y * wv.y + xv.z * wv.z + xv.w * wv.w;
    }
    #pragma unroll
    for (int off = 32; off; off >>= 1) {
        s2 += __shfl_xor(s2, off);
        #pragma unroll
        for (int j = 0; j < 4; ++j) d[j] += __shfl_xor(d[j], off);
    }

    float bs = FLT_MAX; int win = INT_MAX;
    #pragma unroll
    for (int j = 0; j < 4; ++j) {
        float s = (s2 - 2.0f * d[j]) + w2[chosen[j]];
        if (lexlt(s, chosen[j], bs, win)) { bs = s; win = chosen[j]; }
    }

    if (lane == 0) qidx[row] = (float)win;
    *(float4*)(qdata + (size_t)row * E + lane * 4) =
        *(const float4*)(w + (size_t)win * E + lane * 4);
}

// ---------------------------------------------------------------------------
// Main MFMA kernel (round-12 K-loop, unchanged): block = 256 codewords x 256
// x-rows, 512 threads (8 waves), grid (Qn/256, N/256). Per wave acc[4][2]
// (128 cw x 64 xr). K=256 f16 GEMM, BK=64, double-buffered LDS, issue-early
// staging. NEW: last cwg-block per row-band runs the fused finalize.
// ---------------------------------------------------------------------------
__device__ inline void ins4max(float K[4], float k) {
    #pragma unroll
    for (int t = 0; t < 4; ++t) {            // keep K descending
        float mx = fmaxf(K[t], k);
        k = fminf(K[t], k);
        K[t] = mx;
    }
}

union SmemU {
    struct { _Float16 W[256 * 64]; _Float16 X[256 * 64]; } st[2];  // 2 x 64 KB
    float2 mergeS[256 * 2 * 4];                                     // 16 KB overlay
};

__global__ __launch_bounds__(512, 2) void vq_mfma_kernel(
    const _Float16* __restrict__ A16,      // (N, 256)  xh
    const _Float16* __restrict__ B16,      // (Qn, 256) wh_s
    float4* __restrict__ top4,             // (N, 32) packed {k0..k3} desc
    const float* __restrict__ x, const float* __restrict__ w,
    const float* __restrict__ w2,
    float* __restrict__ qdata, float* __restrict__ qidx,
    int* __restrict__ counters)
{
    __shared__ SmemU sm;
    __shared__ int winS;

    const int tid  = threadIdx.x;
    const int wv   = tid >> 6;           // 0..7
    const int lane = tid & 63;
    const int l31  = lane & 31;
    const int lh   = lane >> 5;          // k-half select
    const int cwg  = blockIdx.x;         // codeword group (256 codewords)
    const int rb   = blockIdx.y;         // x-row band (256 rows)

    const int wm = wv & 1;               // codeword half base: wm*128
    const int wn = wv >> 1;              // x-row quarter base: wn*64

    f32x16 acc[4][2];
    #pragma unroll
    for (int m = 0; m < 4; ++m)
        #pragma unroll
        for (int n = 0; n < 2; ++n)
            #pragma unroll
            for (int r = 0; r < 16; ++r) acc[m][n][r] = 0.0f;

    const _Float16* Ab16 = A16 + (size_t)rb  * 256 * 256;
    const _Float16* Bb16 = B16 + (size_t)cwg * 256 * 256;

    const int srow = lane >> 3;   // staging: row-in-8 group
    const int schk = lane & 7;    // staging: dest 16B chunk

    // Stage one BK=64 K-slice of both tiles into buffer b.
    // LDS stays linear per 8-row group (gload_lds constraint); the chunk
    // swizzle lives in the pre-swizzled GLOBAL source (rule #21 involution).
    auto stage = [&](int kt, int b) {
        #pragma unroll
        for (int inst = 0; inst < 4; ++inst) {
            int drow = wv * 32 + inst * 8 + srow;         // 0..255
            int gchk = schk ^ (drow & 7);                 // source chunk swizzle
            const _Float16* gW = Bb16 + (size_t)drow * 256 + kt * 64 + gchk * 8;
            const _Float16* gX = Ab16 + (size_t)drow * 256 + kt * 64 + gchk * 8;
            __builtin_amdgcn_global_load_lds((const GAS void*)gW,
                (LAS void*)(sm.st[b].W + wv * 2048 + inst * 512), 16, 0, 0);
            __builtin_amdgcn_global_load_lds((const GAS void*)gX,
                (LAS void*)(sm.st[b].X + wv * 2048 + inst * 512), 16, 0, 0);
        }
    };

    stage(0, 0);
    __syncthreads();               // prologue drain: buf0 ready

    #pragma unroll
    for (int kt = 0; kt < 4; ++kt) {
        const int b = kt & 1;
        if (kt < 3) stage(kt + 1, b ^ 1);   // issue-early: hides under MFMA below

        const _Float16* Wb = sm.st[b].W;
        const _Float16* Xb = sm.st[b].X;

        __builtin_amdgcn_s_setprio(1);
        #pragma unroll
        for (int s = 0; s < 4; ++s) {
            const int kc = 2 * s + lh;
            half8 wf[4], xf[2];
            #pragma unroll
            for (int m = 0; m < 4; ++m) {
                int fr = wm * 128 + m * 32 + l31;
                wf[m] = *(const half8*)(Wb + fr * 64 + ((kc ^ (fr & 7)) << 3));
            }
            #pragma unroll
            for (int n = 0; n < 2; ++n) {
                int xr = wn * 64 + n * 32 + l31;
                xf[n] = *(const half8*)(Xb + xr * 64 + ((kc ^ (xr & 7)) << 3));
            }
            #pragma unroll
            for (int m = 0; m < 4; ++m)
                #pragma unroll
                for (int n = 0; n < 2; ++n)
                    acc[m][n] = __builtin_amdgcn_mfma_f32_32x32x16_f16(
                        wf[m], xf[n], acc[m][n], 0, 0, 0);
        }
        __builtin_amdgcn_s_setprio(0);
        __syncthreads();           // drains vmcnt(0): next buffer landed;
                                   // also fences reads of buf b before refill
    }

    // ---- epilogue: packed key = (bits(acc) & ~0xFFF) | qg; maximize ----
    // Retention granularity identical to the validated 128^2 version:
    // per lane, top-2 over each {2 m-frags x 16 regs} = 32-codeword group.
    float t1[2][2], t2[2][2];      // [g2][n]
    #pragma unroll
    for (int g2 = 0; g2 < 2; ++g2)
        #pragma unroll
        for (int n = 0; n < 2; ++n) { t1[g2][n] = NEG_INF; t2[g2][n] = NEG_INF; }

    #pragma unroll
    for (int m = 0; m < 4; ++m) {
        const int g2 = m >> 1;
        #pragma unroll
        for (int r = 0; r < 16; ++r) {
            int crow = (r & 3) + 8 * (r >> 2) + 4 * lh;   // C-row mapping (32x32)
            int qg   = cwg * 256 + wm * 128 + m * 32 + crow;  // global codeword id
            #pragma unroll
            for (int n = 0; n < 2; ++n) {
                float pk = __int_as_float(
                    (__float_as_int(acc[m][n][r]) & 0xFFFFF000) | qg);
                t2[g2][n] = __builtin_amdgcn_fmed3f(t1[g2][n], t2[g2][n], pk);
                t1[g2][n] = fmaxf(t1[g2][n], pk);
            }
        }
    }

    __syncthreads();   // staging reads done -> overlay mergeS

    #pragma unroll
    for (int n = 0; n < 2; ++n) {
        int xrow = wn * 64 + n * 32 + l31;
        #pragma unroll
        for (int g2 = 0; g2 < 2; ++g2)
            sm.mergeS[(xrow * 2 + wm) * 4 + (lh * 2 + g2)] =
                make_float2(t1[g2][n], t2[g2][n]);
    }
    __syncthreads();

    {
        int xrow = tid >> 1, cgl = tid & 1;   // 512 threads = 256 rows x 2 cgs
        float K[4] = { NEG_INF, NEG_INF, NEG_INF, NEG_INF };
        #pragma unroll
        for (int sl = 0; sl < 4; ++sl) {
            float2 a = sm.mergeS[(xrow * 2 + cgl) * 4 + sl];
            ins4max(K, a.x);
            ins4max(K, a.y);
        }
        top4[(size_t)(rb * 256 + xrow) * 32 + cwg * 2 + cgl] =
            make_float4(K[0], K[1], K[2], K[3]);
    }

    // ---- fused finalize: last cwg-block per row-band merges + rescores ----
    __threadfence();                       // release: top4 writes visible
    if (tid == 0) winS = atomicAdd(&counters[rb], 1);
    __syncthreads();
    if (winS == Qn / 256 - 1) {            // 16th (last) arriver for this rb
        __threadfence();                   // acquire: order reads after ticket
        #pragma unroll 1
        for (int pass = 0; pass < 32; ++pass) {
            int row = rb * 256 + pass * 8 + wv;   // one wave per row
            finalize_row(row, lane, top4, x, w, w2, qdata, qidx);
        }
    }
}

// ---------------------------------------------------------------------------
// Round-1 fp32 fallback (only if ws_size too small). Passed absmax 0.
// ---------------------------------------------------------------------------
constexpr int FBM = 64, FBN = 128, FBK = 64, FPAD = 4, FTH = 256;

__global__ __launch_bounds__(64) void row_sumsq_kernel(const float* __restrict__ src,
                                                       float* __restrict__ dst) {
    int row = blockIdx.x, lane = threadIdx.x;
    float4 v = ((const float4*)(src + (size_t)row * E))[lane];
    float s = v.x * v.x + v.y * v.y + v.z * v.z + v.w * v.w;
    #pragma unroll
    for (int off = 32; off > 0; off >>= 1) s += __shfl_down(s, off);
    if (lane == 0) dst[row] = s;
}

__global__ __launch_bounds__(FTH) void vq_fallback_kernel(
    const float* __restrict__ x, const float* __restrict__ w,
    const float* __restrict__ x2, const float* __restrict__ w2,
    float* __restrict__ qdata, float* __restrict__ qidx)
{
    __shared__ float xs[FBM][FBK + FPAD];
    __shared__ float ws[FBN][FBK + FPAD];
    __shared__ float redS[FBM][16];
    __shared__ int   redC[FBM][16];
    __shared__ int   bestC[FBM];

    const int tid = threadIdx.x, tr = tid >> 4, tc = tid & 15;
    const int r0 = blockIdx.x * FBM;
    float best[4]; int bidx[4];
    #pragma unroll
    for (int i = 0; i < 4; ++i) { best[i] = FLT_MAX; bidx[i] = 0x7FFFFFFF; }
    float x2r[4];
    #pragma unroll
    for (int i = 0; i < 4; ++i) x2r[i] = x2[r0 + tr + 16 * i];

    for (int qt = 0; qt < Qn / FBN; ++qt) {
        const int c0 = qt * FBN;
        float acc[4][8];
        #pragma unroll
        for (int i = 0; i < 4; ++i)
            #pragma unroll
            for (int j = 0; j < 8; ++j) acc[i][j] = 0.f;
        for (int kt = 0; kt < E / FBK; ++kt) {
            __syncthreads();
            const int kk = (tid & 15) * 4, rr = tid >> 4;
            #pragma unroll
            for (int m = 0; m < 4; ++m)
                *(float4*)&xs[m * 16 + rr][kk] =
                    *(const float4*)(x + (size_t)(r0 + m * 16 + rr) * E + kt * FBK + kk);
            #pragma unroll
            for (int m = 0; m < 8; ++m)
                *(float4*)&ws[m * 16 + rr][kk] =
                    *(const float4*)(w + (size_t)(c0 + m * 16 + rr) * E + kt * FBK + kk);
            __syncthreads();
            #pragma unroll
            for (int k4 = 0; k4 < FBK / 4; ++k4) {
                float4 a[4], bb[8];
                #pragma unroll
                for (int i = 0; i < 4; ++i) a[i] = *(const float4*)&xs[tr + 16 * i][k4 * 4];
                #pragma unroll
                for (int j = 0; j < 8; ++j) bb[j] = *(const float4*)&ws[tc + 16 * j][k4 * 4];
                #pragma unroll
                for (int i = 0; i < 4; ++i)
                    #pragma unroll
                    for (int j = 0; j < 8; ++j) {
                        acc[i][j] += a[i].x * bb[j].x; acc[i][j] += a[i].y * bb[j].y;
                        acc[i][j] += a[i].z * bb[j].z; acc[i][j] += a[i].w * bb[j].w;
                    }
            }
        }
        #pragma unroll
        for (int i = 0; i < 4; ++i)
            #pragma unroll
            for (int j = 0; j < 8; ++j) {
                int c = c0 + tc + 16 * j;
                float s = (x2r[i] - 2.0f * acc[i][j]) + w2[c];
                if (s < best[i]) { best[i] = s; bidx[i] = c; }
            }
    }
    #pragma unroll
    for (int i = 0; i < 4; ++i) { redS[tr + 16 * i][tc] = best[i]; redC[tr + 16 * i][tc] = bidx[i]; }
    __syncthreads();
    if (tid < FBM) {
        float bs = FLT_MAX; int bc = 0x7FFFFFFF;
        #pragma unroll
        for (int t = 0; t < 16; ++t) {
            float s = redS[tid][t]; int c = redC[tid][t];
            if (s < bs || (s == bs && c < bc)) { bs = s; bc = c; }
        }
        qidx[r0 + tid] = (float)bc; bestC[tid] = bc;
    }
    __syncthreads();
    for (int it = 0; it < FBM / 4; ++it) {
        int row = it * 4 + (tid >> 6), c = bestC[row], kk = (tid & 63) * 4;
        *(float4*)(qdata + (size_t)(r0 + row) * E + kk) = *(const float4*)(w + (size_t)c * E + kk);
    }
}

// ---------------------------------------------------------------------------
extern "C" void kernel_launch(void* const* d_in, const int* in_sizes, int n_in,
                              void* d_out, int out_size, void* d_ws, size_t ws_size,
                              hipStream_t stream) {
    const float* x = (const float*)d_in[0];
    const float* w = (const float*)d_in[1];
    const int N = in_sizes[0] / E;                      // 32768

    float* qdata = (float*)d_out;
    float* qidx  = (float*)d_out + (size_t)N * E;

    size_t off = 0;
    auto carve = [&](size_t bytes) { size_t p = off; off += (bytes + 255) & ~(size_t)255; return p; };
    size_t oA16 = carve((size_t)N  * 256 * sizeof(_Float16));     // 16.8 MB
    size_t oB16 = carve((size_t)Qn * 256 * sizeof(_Float16));     //  2.1 MB
    size_t ow2  = carve((size_t)Qn * sizeof(float));
    size_t oT   = carve((size_t)N * 32 * sizeof(float4));         // 16.8 MB
    size_t oCnt = carve(256 * sizeof(int));                       // rb tickets
    size_t ox2f = carve((size_t)N * sizeof(float));               // fallback only

    if (ws_size >= off && (N % 256) == 0) {
        char* ws = (char*)d_ws;
        _Float16* A16 = (_Float16*)(ws + oA16);
        _Float16* B16 = (_Float16*)(ws + oB16);
        float* w2    = (float*)(ws + ow2);
        float4* top4 = (float4*)(ws + oT);
        int* counters = (int*)(ws + oCnt);

        prep_kernel<<<N / 4 + Qn / 4, 256, 0, stream>>>(x, w, A16, B16, w2, counters, N / 4);
        vq_mfma_kernel<<<dim3(Qn / 256, N / 256), 512, 0, stream>>>(
            A16, B16, top4, x, w, w2, qdata, qidx, counters);
    } else {
        float* x2 = (float*)d_ws;
        float* w2 = x2 + N;
        row_sumsq_kernel<<<N, 64, 0, stream>>>(x, x2);
        row_sumsq_kernel<<<Qn, 64, 0, stream>>>(w, w2);
        vq_fallback_kernel<<<N / FBM, FTH, 0, stream>>>(x, w, x2, w2, qdata, qidx);
    }
}

// Round 4
// 188.271 us; speedup vs baseline: 7.3220x; 7.3220x over previous
//
#include <hip/hip_runtime.h>
#include <cfloat>
#include <climits>

// Problem constants: x (16,2048,256) fp32 -> N=32768 rows; weight (4096,256) fp32.
constexpr int E  = 256;    // quantizing_dim
constexpr int Qn = 4096;   // num_quantizing
constexpr float WSCALE = 4096.0f;   // 2^12 exact pow2 (keeps f16 products well-scaled)

// Round 15: revert round-14's fused finalize (per-block __threadfence -> L2
// writeback/invalidate storm: 199 -> 1379 us). Back to the validated
// three-kernel round-12 structure, with ONE schedule change in the K-loop
// (T4, counted vmcnt): staging moves to END of iteration (stage kt+2 after a
// WAR barrier), RAW gate at top is s_waitcnt vmcnt(8) + s_barrier -- "every
// wave's oldest 8 loads done" collectively means the tile is staged; no wave
// ever drains vmcnt to 0 mid-loop (round 12's __syncthreads did, stalling all
// waves on their own just-issued loads each iteration). 2 barriers/iter, both
// drain-free. Numerics byte-identical to round 12.

typedef _Float16 half8  __attribute__((ext_vector_type(8)));
typedef _Float16 half4v __attribute__((ext_vector_type(4)));
typedef float    f32x16 __attribute__((ext_vector_type(16)));

#define GAS __attribute__((address_space(1)))
#define LAS __attribute__((address_space(3)))

#define NEG_INF __int_as_float(0xFF800000)

__device__ inline bool lexlt(float a, int ai, float b, int bi) {
    return a < b || (a == b && ai < bi);
}

// ---------------------------------------------------------------------------
// Prep: one 64-lane wave per row (x and w). Emits f16 operand; sumsq only for w.
// (unchanged, validated)
// ---------------------------------------------------------------------------
__global__ __launch_bounds__(256) void prep_kernel(
    const float* __restrict__ x, const float* __restrict__ w,
    _Float16* __restrict__ A16, _Float16* __restrict__ B16,
    float* __restrict__ w2, int nxblocks)
{
    int blk  = blockIdx.x;
    int sub  = threadIdx.x >> 6;
    int lane = threadIdx.x & 63;
    bool isX = blk < nxblocks;
    int row  = (isX ? blk : blk - nxblocks) * 4 + sub;

    const float* src = isX ? x : w;
    float4 v = *(const float4*)(src + (size_t)row * E + lane * 4);

    if (!isX) {
        float s = v.x * v.x + v.y * v.y + v.z * v.z + v.w * v.w;   // UNSCALED sumsq
        #pragma unroll
        for (int off = 32; off; off >>= 1) s += __shfl_xor(s, off);
        if (lane == 0) w2[row] = s;
    }

    float sc = isX ? 1.0f : WSCALE;                            // exact pow2
    half4v h = { (_Float16)(v.x * sc), (_Float16)(v.y * sc),
                 (_Float16)(v.z * sc), (_Float16)(v.w * sc) };
    _Float16* dst16 = (isX ? A16 : B16) + (size_t)row * 256;
    *(half4v*)(dst16 + lane * 4) = h;
}

// ---------------------------------------------------------------------------
// Main MFMA kernel: block = 256 codewords x 256 x-rows, 512 threads (8 waves),
// grid (Qn/256, N/256). Per wave acc[4][2] (128 cw x 64 xr) of 32x32x16 f16.
// K=256 f16 GEMM, BK=64, double-buffered LDS, counted-vmcnt schedule.
// ---------------------------------------------------------------------------
__device__ inline void ins4max(float K[4], float k) {
    #pragma unroll
    for (int t = 0; t < 4; ++t) {            // keep K descending
        float mx = fmaxf(K[t], k);
        k = fminf(K[t], k);
        K[t] = mx;
    }
}

union SmemU {
    struct { _Float16 W[256 * 64]; _Float16 X[256 * 64]; } st[2];  // 2 x 64 KB
    float2 mergeS[256 * 2 * 4];                                     // 16 KB overlay
};

__global__ __launch_bounds__(512, 2) void vq_mfma_kernel(
    const _Float16* __restrict__ A16,      // (N, 256)  xh
    const _Float16* __restrict__ B16,      // (Qn, 256) wh_s
    float4* __restrict__ top4)             // (N, 32) packed {k0,k1,k2,k3} desc
{
    __shared__ SmemU sm;

    const int tid  = threadIdx.x;
    const int w    = tid >> 6;           // 0..7
    const int lane = tid & 63;
    const int l31  = lane & 31;
    const int lh   = lane >> 5;          // k-half select
    const int cwg  = blockIdx.x;         // codeword group (256 codewords)
    const int rb   = blockIdx.y;         // x-row band (256 rows)

    const int wm = w & 1;                // codeword half base: wm*128
    const int wn = w >> 1;               // x-row quarter base: wn*64

    f32x16 acc[4][2];
    #pragma unroll
    for (int m = 0; m < 4; ++m)
        #pragma unroll
        for (int n = 0; n < 2; ++n)
            #pragma unroll
            for (int r = 0; r < 16; ++r) acc[m][n][r] = 0.0f;

    const _Float16* Ab16 = A16 + (size_t)rb  * 256 * 256;
    const _Float16* Bb16 = B16 + (size_t)cwg * 256 * 256;

    const int srow = lane >> 3;   // staging: row-in-8 group
    const int schk = lane & 7;    // staging: dest 16B chunk

    // Stage one BK=64 K-slice of both tiles into buffer b (8 gload_lds/wave).
    // LDS stays linear per 8-row group (gload_lds constraint); the chunk
    // swizzle lives in the pre-swizzled GLOBAL source (rule #21 involution).
    auto stage = [&](int kt, int b) {
        #pragma unroll
        for (int inst = 0; inst < 4; ++inst) {
            int drow = w * 32 + inst * 8 + srow;          // 0..255
            int gchk = schk ^ (drow & 7);                 // source chunk swizzle
            const _Float16* gW = Bb16 + (size_t)drow * 256 + kt * 64 + gchk * 8;
            const _Float16* gX = Ab16 + (size_t)drow * 256 + kt * 64 + gchk * 8;
            __builtin_amdgcn_global_load_lds((const GAS void*)gW,
                (LAS void*)(sm.st[b].W + w * 2048 + inst * 512), 16, 0, 0);
            __builtin_amdgcn_global_load_lds((const GAS void*)gX,
                (LAS void*)(sm.st[b].X + w * 2048 + inst * 512), 16, 0, 0);
        }
    };

    // prologue: both buffers' stages in flight (16 loads/wave), no drain.
    stage(0, 0);
    stage(1, 1);

    #pragma unroll
    for (int kt = 0; kt < 4; ++kt) {
        const int b = kt & 1;

        // RAW gate: tile kt staged by ALL waves. Per-wave outstanding here:
        // kt<3 -> {stage(kt), stage(kt+1)} = 16, oldest 8 = stage(kt);
        // kt=3 -> only stage(3) = 8 outstanding.
        if (kt < 3) asm volatile("s_waitcnt vmcnt(8)" ::: "memory");
        else        asm volatile("s_waitcnt vmcnt(0)" ::: "memory");
        __builtin_amdgcn_s_barrier();
        asm volatile("" ::: "memory");

        const _Float16* Wb = sm.st[b].W;
        const _Float16* Xb = sm.st[b].X;

        __builtin_amdgcn_s_setprio(1);
        #pragma unroll
        for (int s = 0; s < 4; ++s) {
            const int kc = 2 * s + lh;
            half8 wf[4], xf[2];
            #pragma unroll
            for (int m = 0; m < 4; ++m) {
                int fr = wm * 128 + m * 32 + l31;
                wf[m] = *(const half8*)(Wb + fr * 64 + ((kc ^ (fr & 7)) << 3));
            }
            #pragma unroll
            for (int n = 0; n < 2; ++n) {
                int xr = wn * 64 + n * 32 + l31;
                xf[n] = *(const half8*)(Xb + xr * 64 + ((kc ^ (xr & 7)) << 3));
            }
            #pragma unroll
            for (int m = 0; m < 4; ++m)
                #pragma unroll
                for (int n = 0; n < 2; ++n)
                    acc[m][n] = __builtin_amdgcn_mfma_f32_32x32x16_f16(
                        wf[m], xf[n], acc[m][n], 0, 0, 0);
        }
        __builtin_amdgcn_s_setprio(0);

        // WAR gate + refill: all waves' ds_reads of buf b are complete (data
        // consumed into registers before their dependent MFMAs issued), so
        // buf b may be overwritten with tile kt+2. No vmcnt drain here.
        if (kt < 2) {
            asm volatile("" ::: "memory");
            __builtin_amdgcn_s_barrier();
            asm volatile("" ::: "memory");
            stage(kt + 2, b);
        }
    }

    // ---- epilogue: packed key = (bits(acc) & ~0xFFF) | qg; maximize ----
    // Retention granularity identical to the validated 128^2 version:
    // per lane, top-2 over each {2 m-frags x 16 regs} = 32-codeword group.
    float t1[2][2], t2[2][2];      // [g2][n]
    #pragma unroll
    for (int g2 = 0; g2 < 2; ++g2)
        #pragma unroll
        for (int n = 0; n < 2; ++n) { t1[g2][n] = NEG_INF; t2[g2][n] = NEG_INF; }

    #pragma unroll
    for (int m = 0; m < 4; ++m) {
        const int g2 = m >> 1;
        #pragma unroll
        for (int r = 0; r < 16; ++r) {
            int crow = (r & 3) + 8 * (r >> 2) + 4 * lh;   // C-row mapping (32x32)
            int qg   = cwg * 256 + wm * 128 + m * 32 + crow;  // global codeword id
            #pragma unroll
            for (int n = 0; n < 2; ++n) {
                float pk = __int_as_float(
                    (__float_as_int(acc[m][n][r]) & 0xFFFFF000) | qg);
                t2[g2][n] = __builtin_amdgcn_fmed3f(t1[g2][n], t2[g2][n], pk);
                t1[g2][n] = fmaxf(t1[g2][n], pk);
            }
        }
    }

    __syncthreads();   // staging reads done -> overlay mergeS (full drain ok here)

    #pragma unroll
    for (int n = 0; n < 2; ++n) {
        int xrow = wn * 64 + n * 32 + l31;
        #pragma unroll
        for (int g2 = 0; g2 < 2; ++g2)
            sm.mergeS[(xrow * 2 + wm) * 4 + (lh * 2 + g2)] =
                make_float2(t1[g2][n], t2[g2][n]);
    }
    __syncthreads();

    {
        int xrow = tid >> 1, cgl = tid & 1;   // 512 threads = 256 rows x 2 cgs
        float K[4] = { NEG_INF, NEG_INF, NEG_INF, NEG_INF };
        #pragma unroll
        for (int sl = 0; sl < 4; ++sl) {
            float2 a = sm.mergeS[(xrow * 2 + cgl) * 4 + sl];
            ins4max(K, a.x);
            ins4max(K, a.y);
        }
        top4[(size_t)(rb * 256 + xrow) * 32 + cwg * 2 + cgl] =
            make_float4(K[0], K[1], K[2], K[3]);
    }
}

// ---------------------------------------------------------------------------
// Finalize: per row, 32 cg x top-4 packed candidates -> global top-4 by packed
// key (wave-max passes w/ bitwise invalidation) -> exact fp32 rescore
// (reference formula + first-index tie-break), write outputs. (unchanged)
// ---------------------------------------------------------------------------
__global__ __launch_bounds__(256) void finalize_kernel(
    const float4* __restrict__ top4, const float* __restrict__ x,
    const float* __restrict__ w, const float* __restrict__ w2,
    float* __restrict__ qdata, float* __restrict__ qidx)
{
    int row  = blockIdx.x * 4 + (threadIdx.x >> 6);
    int lane = threadIdx.x & 63;

    float cand[4];
    if (lane < 32) {
        float4 c4 = top4[(size_t)row * 32 + lane];
        cand[0] = c4.x; cand[1] = c4.y; cand[2] = c4.z; cand[3] = c4.w;
    } else {
        cand[0] = cand[1] = cand[2] = cand[3] = NEG_INF;
    }

    int chosen[4];
    #pragma unroll
    for (int p = 0; p < 4; ++p) {
        float cur = fmaxf(fmaxf(cand[0], cand[1]), fmaxf(cand[2], cand[3]));
        #pragma unroll
        for (int off = 32; off; off >>= 1)
            cur = fmaxf(cur, __shfl_xor(cur, off));
        int curb = __float_as_int(cur);
        chosen[p] = curb & 0xFFF;
        #pragma unroll
        for (int j = 0; j < 4; ++j)
            if (__float_as_int(cand[j]) == curb) cand[j] = NEG_INF;
    }

    // exact fp32 rescore of the 4 survivors (round-1-validated formula);
    // X2 via the same data layout + butterfly order as the old prep reduction.
    float4 xv = *(const float4*)(x + (size_t)row * E + lane * 4);
    float s2 = xv.x * xv.x + xv.y * xv.y + xv.z * xv.z + xv.w * xv.w;
    float d[4];
    #pragma unroll
    for (int j = 0; j < 4; ++j) {
        float4 wv = *(const float4*)(w + (size_t)chosen[j] * E + lane * 4);
        d[j] = xv.x * wv.x + xv.y * wv.y + xv.z * wv.z + xv.w * wv.w;
    }
    #pragma unroll
    for (int off = 32; off; off >>= 1) {
        s2 += __shfl_xor(s2, off);
        #pragma unroll
        for (int j = 0; j < 4; ++j) d[j] += __shfl_xor(d[j], off);
    }

    float bs = FLT_MAX; int win = INT_MAX;
    #pragma unroll
    for (int j = 0; j < 4; ++j) {
        float s = (s2 - 2.0f * d[j]) + w2[chosen[j]];
        if (lexlt(s, chosen[j], bs, win)) { bs = s; win = chosen[j]; }
    }

    if (lane == 0) qidx[row] = (float)win;
    *(float4*)(qdata + (size_t)row * E + lane * 4) =
        *(const float4*)(w + (size_t)win * E + lane * 4);
}

// ---------------------------------------------------------------------------
// Round-1 fp32 fallback (only if ws_size too small). Passed absmax 0.
// ---------------------------------------------------------------------------
constexpr int FBM = 64, FBN = 128, FBK = 64, FPAD = 4, FTH = 256;

__global__ __launch_bounds__(64) void row_sumsq_kernel(const float* __restrict__ src,
                                                       float* __restrict__ dst) {
    int row = blockIdx.x, lane = threadIdx.x;
    float4 v = ((const float4*)(src + (size_t)row * E))[lane];
    float s = v.x * v.x + v.y * v.y + v.z * v.z + v.w * v.w;
    #pragma unroll
    for (int off = 32; off > 0; off >>= 1) s += __shfl_down(s, off);
    if (lane == 0) dst[row] = s;
}

__global__ __launch_bounds__(FTH) void vq_fallback_kernel(
    const float* __restrict__ x, const float* __restrict__ w,
    const float* __restrict__ x2, const float* __restrict__ w2,
    float* __restrict__ qdata, float* __restrict__ qidx)
{
    __shared__ float xs[FBM][FBK + FPAD];
    __shared__ float ws[FBN][FBK + FPAD];
    __shared__ float redS[FBM][16];
    __shared__ int   redC[FBM][16];
    __shared__ int   bestC[FBM];

    const int tid = threadIdx.x, tr = tid >> 4, tc = tid & 15;
    const int r0 = blockIdx.x * FBM;
    float best[4]; int bidx[4];
    #pragma unroll
    for (int i = 0; i < 4; ++i) { best[i] = FLT_MAX; bidx[i] = 0x7FFFFFFF; }
    float x2r[4];
    #pragma unroll
    for (int i = 0; i < 4; ++i) x2r[i] = x2[r0 + tr + 16 * i];

    for (int qt = 0; qt < Qn / FBN; ++qt) {
        const int c0 = qt * FBN;
        float acc[4][8];
        #pragma unroll
        for (int i = 0; i < 4; ++i)
            #pragma unroll
            for (int j = 0; j < 8; ++j) acc[i][j] = 0.f;
        for (int kt = 0; kt < E / FBK; ++kt) {
            __syncthreads();
            const int kk = (tid & 15) * 4, rr = tid >> 4;
            #pragma unroll
            for (int m = 0; m < 4; ++m)
                *(float4*)&xs[m * 16 + rr][kk] =
                    *(const float4*)(x + (size_t)(r0 + m * 16 + rr) * E + kt * FBK + kk);
            #pragma unroll
            for (int m = 0; m < 8; ++m)
                *(float4*)&ws[m * 16 + rr][kk] =
                    *(const float4*)(w + (size_t)(c0 + m * 16 + rr) * E + kt * FBK + kk);
            __syncthreads();
            #pragma unroll
            for (int k4 = 0; k4 < FBK / 4; ++k4) {
                float4 a[4], bb[8];
                #pragma unroll
                for (int i = 0; i < 4; ++i) a[i] = *(const float4*)&xs[tr + 16 * i][k4 * 4];
                #pragma unroll
                for (int j = 0; j < 8; ++j) bb[j] = *(const float4*)&ws[tc + 16 * j][k4 * 4];
                #pragma unroll
                for (int i = 0; i < 4; ++i)
                    #pragma unroll
                    for (int j = 0; j < 8; ++j) {
                        acc[i][j] += a[i].x * bb[j].x; acc[i][j] += a[i].y * bb[j].y;
                        acc[i][j] += a[i].z * bb[j].z; acc[i][j] += a[i].w * bb[j].w;
                    }
            }
        }
        #pragma unroll
        for (int i = 0; i < 4; ++i)
            #pragma unroll
            for (int j = 0; j < 8; ++j) {
                int c = c0 + tc + 16 * j;
                float s = (x2r[i] - 2.0f * acc[i][j]) + w2[c];
                if (s < best[i]) { best[i] = s; bidx[i] = c; }
            }
    }
    #pragma unroll
    for (int i = 0; i < 4; ++i) { redS[tr + 16 * i][tc] = best[i]; redC[tr + 16 * i][tc] = bidx[i]; }
    __syncthreads();
    if (tid < FBM) {
        float bs = FLT_MAX; int bc = 0x7FFFFFFF;
        #pragma unroll
        for (int t = 0; t < 16; ++t) {
            float s = redS[tid][t]; int c = redC[tid][t];
            if (s < bs || (s == bs && c < bc)) { bs = s; bc = c; }
        }
        qidx[r0 + tid] = (float)bc; bestC[tid] = bc;
    }
    __syncthreads();
    for (int it = 0; it < FBM / 4; ++it) {
        int row = it * 4 + (tid >> 6), c = bestC[row], kk = (tid & 63) * 4;
        *(float4*)(qdata + (size_t)(r0 + row) * E + kk) = *(const float4*)(w + (size_t)c * E + kk);
    }
}

// ---------------------------------------------------------------------------
extern "C" void kernel_launch(void* const* d_in, const int* in_sizes, int n_in,
                              void* d_out, int out_size, void* d_ws, size_t ws_size,
                              hipStream_t stream) {
    const float* x = (const float*)d_in[0];
    const float* w = (const float*)d_in[1];
    const int N = in_sizes[0] / E;                      // 32768

    float* qdata = (float*)d_out;
    float* qidx  = (float*)d_out + (size_t)N * E;

    size_t off = 0;
    auto carve = [&](size_t bytes) { size_t p = off; off += (bytes + 255) & ~(size_t)255; return p; };
    size_t oA16 = carve((size_t)N  * 256 * sizeof(_Float16));     // 16.8 MB
    size_t oB16 = carve((size_t)Qn * 256 * sizeof(_Float16));     //  2.1 MB
    size_t ow2  = carve((size_t)Qn * sizeof(float));
    size_t oT   = carve((size_t)N * 32 * sizeof(float4));         // 16.8 MB
    size_t ox2f = carve((size_t)N * sizeof(float));               // fallback only

    if (ws_size >= off && (N % 256) == 0) {
        char* ws = (char*)d_ws;
        _Float16* A16 = (_Float16*)(ws + oA16);
        _Float16* B16 = (_Float16*)(ws + oB16);
        float* w2    = (float*)(ws + ow2);
        float4* top4 = (float4*)(ws + oT);

        prep_kernel<<<N / 4 + Qn / 4, 256, 0, stream>>>(x, w, A16, B16, w2, N / 4);
        vq_mfma_kernel<<<dim3(Qn / 256, N / 256), 512, 0, stream>>>(A16, B16, top4);
        finalize_kernel<<<N / 4, 256, 0, stream>>>(top4, x, w, w2, qdata, qidx);
    } else {
        float* x2 = (float*)d_ws;
        float* w2 = x2 + N;
        row_sumsq_kernel<<<N, 64, 0, stream>>>(x, x2);
        row_sumsq_kernel<<<Qn, 64, 0, stream>>>(w, w2);
        vq_fallback_kernel<<<N / FBM, FTH, 0, stream>>>(x, w, x2, w2, qdata, qidx);
    }
}